// Round 5
// baseline (1186.700 us; speedup 1.0000x reference)
//
#include <hip/hip_runtime.h>
#include <hip/hip_bf16.h>
#include <stdint.h>

#define NN 8192
#define FD 690
#define NH 3
#define KPAD 704   // F_IN padded to mult of 64
#define OPAD 768   // F_OUT padded to mult of 128 (row FD holds constant 1 -> Z column)
#define USTRIDE 704
#define KS 4       // K-split factor for k_pv
#define LOG2E 1.4426950408889634f

typedef __attribute__((ext_vector_type(8))) short bf16x8;
typedef __attribute__((ext_vector_type(4))) float f32x4;

typedef __attribute__((address_space(1))) const void gas_t;
typedef __attribute__((address_space(3))) void las_t;

__device__ __forceinline__ void async_ld16(const void* g, void* l) {
  __builtin_amdgcn_global_load_lds((gas_t*)g, (las_t*)l, 16, 0, 0);
}

__device__ __forceinline__ float bf2f(unsigned short u) {
  return __uint_as_float(((unsigned int)u) << 16);
}
__device__ __forceinline__ unsigned short f2bf(float f) {
  __hip_bfloat16 h = __float2bfloat16(f);
  return *reinterpret_cast<unsigned short*>(&h);
}
// r = bit[lane] of (hi:lo) ? e : 0 — mask forced scalar via readfirstlane upstream
__device__ __forceinline__ float selbit(float e, uint32_t lo, uint32_t hi) {
  uint64_t m = ((uint64_t)hi << 32) | lo;
  float r;
  asm("v_cndmask_b32 %0, 0, %1, %2" : "=v"(r) : "v"(e), "s"(m));
  return r;
}

// ---------- cast / pad ----------
__global__ __launch_bounds__(256) void k_cast_x(const float* __restrict__ x,
                                                unsigned short* __restrict__ xb) {
  int idx = blockIdx.x * 256 + threadIdx.x;
  if (idx >= NN * KPAD) return;
  int n = idx / KPAD, f = idx - n * KPAD;
  float v = (f < FD) ? x[(size_t)n * FD + f] : 0.f;
  xb[idx] = f2bf(v);
}

__global__ __launch_bounds__(256) void k_cast_wt(const float* __restrict__ W,
                                                 unsigned short* __restrict__ wt) {
  int idx = blockIdx.x * 256 + threadIdx.x;
  if (idx >= NH * OPAD * KPAD) return;
  int h = idx / (OPAD * KPAD);
  int rem = idx - h * OPAD * KPAD;
  int o = rem / KPAD, f = rem - o * KPAD;
  float v = (o < FD && f < FD) ? W[((size_t)h * FD + f) * FD + o] : 0.f;
  wt[idx] = f2bf(v);
}

// ---------- adjacency -> bitmask ----------
__global__ __launch_bounds__(256) void k_pack(const int* __restrict__ adj,
                                              uint64_t* __restrict__ bm) {
  int wid = (blockIdx.x * 256 + threadIdx.x) >> 6;
  int lane = threadIdx.x & 63;
  int i = wid >> 7, wj = wid & 127;
  int v = adj[(int64_t)i * NN + wj * 64 + lane];
  uint64_t m = __ballot(v > 0);
  if (lane == 0) bm[i * 128 + wj] = m;
}

// ---------- WhT[h][o][n] = sum_f x[n][f] W[h][f][o]  (bf16 out; row FD = 1.0) ----------
__global__ __launch_bounds__(512) void k_gemm_wht(const unsigned short* __restrict__ wt,
                                                  const unsigned short* __restrict__ xb,
                                                  unsigned short* __restrict__ wht) {
  const int m0 = blockIdx.x * 128;   // o
  const int n0 = blockIdx.y * 256;   // node
  const int h  = blockIdx.z;
  const int tid = threadIdx.x;
  const int w = tid >> 6, l = tid & 63;
  const int wm = w >> 2, wn = w & 3;
  __shared__ unsigned short As[128 * 64];
  __shared__ unsigned short Bs[256 * 64];
  const unsigned short* Ag = wt + (size_t)h * OPAD * KPAD;
  f32x4 acc[4][4] = {};
  for (int kt = 0; kt < KPAD / 64; ++kt) {
    const int k0 = kt * 64;
#pragma unroll
    for (int r = 0; r < 2; ++r) {
      const unsigned short* g = Ag + (size_t)(m0 + r * 64 + w * 8 + (l >> 3)) * KPAD + k0 + (l & 7) * 8;
      async_ld16(g, &As[(r * 64 + w * 8) * 64]);
    }
#pragma unroll
    for (int r = 0; r < 4; ++r) {
      const unsigned short* g = xb + (size_t)(n0 + r * 64 + w * 8 + (l >> 3)) * KPAD + k0 + (l & 7) * 8;
      async_ld16(g, &Bs[(r * 64 + w * 8) * 64]);
    }
    __syncthreads();
#pragma unroll
    for (int ks = 0; ks < 2; ++ks) {
      bf16x8 af[4], bfr[4];
#pragma unroll
      for (int mi = 0; mi < 4; ++mi)
        af[mi] = *reinterpret_cast<const bf16x8*>(
            &As[(wm * 64 + mi * 16 + (l & 15)) * 64 + ks * 32 + (l >> 4) * 8]);
#pragma unroll
      for (int ni = 0; ni < 4; ++ni)
        bfr[ni] = *reinterpret_cast<const bf16x8*>(
            &Bs[(wn * 64 + ni * 16 + (l & 15)) * 64 + ks * 32 + (l >> 4) * 8]);
#pragma unroll
      for (int mi = 0; mi < 4; ++mi)
#pragma unroll
        for (int ni = 0; ni < 4; ++ni)
          acc[mi][ni] = __builtin_amdgcn_mfma_f32_16x16x32_bf16(af[mi], bfr[ni], acc[mi][ni], 0, 0, 0);
    }
    __syncthreads();
  }
  unsigned short* Wh = wht + (size_t)h * OPAD * NN;
#pragma unroll
  for (int mi = 0; mi < 4; ++mi)
#pragma unroll
    for (int j = 0; j < 4; ++j) {
      int o = m0 + wm * 64 + mi * 16 + (l >> 4) * 4 + j;
#pragma unroll
      for (int ni = 0; ni < 4; ++ni) {
        int n = n0 + wn * 64 + ni * 16 + (l & 15);
        float val = (o == FD) ? 1.0f : acc[mi][ni][j];  // pad rows are exactly 0; row FD = ones
        Wh[(size_t)o * NN + n] = f2bf(val);
      }
    }
}

// ---------- per (head,node): E=2^(a*log2e), F=2^(0.2*a*log2e) for both halves ----------
__global__ __launch_bounds__(256) void k_a1a2(const unsigned short* __restrict__ wht,
                                              const float* __restrict__ a,
                                              float* __restrict__ e1s, float* __restrict__ f1s,
                                              float* __restrict__ e2s, float* __restrict__ f2s) {
  const int h = blockIdx.y;
  const int n = blockIdx.x * 256 + threadIdx.x;
  const unsigned short* Wp = wht + (size_t)h * OPAD * NN + n;
  const float* ap = a + h * 2 * FD;
  float s1 = 0.f, s2 = 0.f;
  for (int o = 0; o < FD; ++o) {
    float wv = bf2f(Wp[(size_t)o * NN]);
    s1 += wv * ap[o];
    s2 += wv * ap[FD + o];
  }
  e1s[h * NN + n] = exp2f(s1 * LOG2E);
  f1s[h * NN + n] = exp2f(0.2f * s1 * LOG2E);
  e2s[h * NN + n] = exp2f(s2 * LOG2E);
  f2s[h * NN + n] = exp2f(0.2f * s2 * LOG2E);
}

// ---------- PV: U[h][i][n] += sum_{j in kseg} w_ij WhT[n][j] ; column FD gives Z_i ----------
// w_ij = max(E1_i*E2_j, F1_i*F2_j)  (== exp2(log2e*lrelu(a1_i+a2_j)), exp2 monotone)
// BK=32 software pipeline at constant 48KB LDS:
//   As[128][64]: column halves ping-pong (A-gen writes nxt while MFMA reads cur)
//   Bs[2][256][32]: gload_lds double buffer (linear dest, source k-block pre-swizzled)
//   ONE barrier per iteration; vmcnt(0) drain covered by A-gen+MFMA of the same iter.
__global__ __launch_bounds__(512) void k_pv(const unsigned short* __restrict__ wht,
                                            const float* __restrict__ e1s,
                                            const float* __restrict__ f1s,
                                            const float* __restrict__ e2s,
                                            const float* __restrict__ f2s,
                                            const uint64_t* __restrict__ bm,
                                            float* __restrict__ U) {
  const int m0 = blockIdx.x * 128;          // node rows i
  const int n0 = blockIdx.y * 256;          // feature cols
  const int h    = blockIdx.z / KS;
  const int kseg = blockIdx.z % KS;
  const int tid = threadIdx.x;
  const int w = tid >> 6, l = tid & 63;
  const int wu = __builtin_amdgcn_readfirstlane(w);
  const int wm = w >> 2, wn = w & 3;
  __shared__ unsigned short As[128 * 64];       // 16KB, halves at elem cols [0,32),[32,64) swizzled
  __shared__ unsigned short Bs[2][256 * 32];    // 2 x 16KB
  const unsigned short* Bg = wht + (size_t)h * OPAD * NN;
  const uint64_t* bmw = bm + (size_t)(m0 + wu * 16) * 128;
  const int rj = l >> 5;                    // which of the row pair this lane handles
  const int kl = l & 31;                    // k within the 32-wide window
  float e1v[8], f1v[8];
#pragma unroll
  for (int s = 0; s < 8; ++s) {
    e1v[s] = e1s[h * NN + m0 + wu * 16 + 2 * s + rj];
    f1v[s] = f1s[h * NN + m0 + wu * 16 + 2 * s + rj];
  }

  // stage B window t into Bs[buf]: linear dest, source block pre-swizzled
  auto stage = [&](int buf, int t) {
    const int k0 = t * 32;
#pragma unroll
    for (int call = 0; call < 2; ++call) {
      int c = wu * 128 + call * 64 + l;     // 16B-chunk index in [0,1024)
      int row = c >> 2;
      int kb  = c & 3;
      int kbs = kb ^ (row & 3) ^ ((row >> 2) & 3);
      const unsigned short* g = Bg + (size_t)(n0 + row) * NN + k0 + kbs * 8;
      async_ld16(g, &Bs[buf][(size_t)c * 8]);
    }
  };

  // generate A window t into column half `half`
  auto genA = [&](int half, int t) {
    const int k0 = t * 32;
    const float e2v = e2s[h * NN + k0 + kl];
    const float f2v = f2s[h * NN + k0 + kl];
    const int chunk = t >> 1;
    const int hi = t & 1;
#pragma unroll
    for (int s = 0; s < 8; ++s) {
      uint64_t mr0 = bmw[(size_t)(2 * s) * 128 + chunk];
      uint64_t mr1 = bmw[(size_t)(2 * s + 1) * 128 + chunk];
      uint32_t b0 = (uint32_t)(hi ? (mr0 >> 32) : mr0);
      uint32_t b1 = (uint32_t)(hi ? (mr1 >> 32) : mr1);
      b0 = __builtin_amdgcn_readfirstlane(b0);
      b1 = __builtin_amdgcn_readfirstlane(b1);
      float e = fmaxf(e1v[s] * e2v, f1v[s] * f2v);
      e = selbit(e, b0, b1);                 // lanes<32: bit kl of row 2s; lanes>=32: row 2s+1
      int row = wu * 16 + 2 * s + rj;
      int phys = (half * 4 + (kl >> 3)) ^ (row & 7);
      As[row * 64 + phys * 8 + (l & 7)] = f2bf(e);
    }
  };

  const int kt0 = kseg * (NN / 32 / KS);
  const int ktend = kt0 + NN / 32 / KS;

  f32x4 acc[4][4] = {};

  // prologue: fill buffer/half 0 for t0
  stage(0, kt0);
  genA(0, kt0);
  asm volatile("s_waitcnt vmcnt(0) lgkmcnt(0)" ::: "memory");
  __builtin_amdgcn_s_barrier();
  __builtin_amdgcn_sched_barrier(0);

  int cur = 0;
  for (int t = kt0; t < ktend; ++t) {
    const int nxt = cur ^ 1;
    if (t + 1 < ktend) {
      stage(nxt, t + 1);        // async loads in flight across the whole iteration
      genA(nxt, t + 1);         // VALU, overlaps MFMA below (independent pipes)
    }
    // MFMA on window t (half/buffer cur)
    __builtin_amdgcn_s_setprio(1);
    bf16x8 af[4];
#pragma unroll
    for (int mi = 0; mi < 4; ++mi) {
      int row = wm * 64 + mi * 16 + (l & 15);
      int phys = (cur * 4 + (l >> 4)) ^ (row & 7);
      af[mi] = *reinterpret_cast<const bf16x8*>(&As[row * 64 + phys * 8]);
    }
#pragma unroll
    for (int ni = 0; ni < 4; ++ni) {
      int row = wn * 64 + ni * 16 + (l & 15);
      int phys = (l >> 4) ^ (row & 3) ^ ((row >> 2) & 3);
      bf16x8 bfr = *reinterpret_cast<const bf16x8*>(&Bs[cur][row * 32 + phys * 8]);
#pragma unroll
      for (int mi = 0; mi < 4; ++mi)
        acc[mi][ni] = __builtin_amdgcn_mfma_f32_16x16x32_bf16(af[mi], bfr, acc[mi][ni], 0, 0, 0);
    }
    __builtin_amdgcn_s_setprio(0);

    asm volatile("s_waitcnt vmcnt(0) lgkmcnt(0)" ::: "memory");
    __builtin_amdgcn_s_barrier();
    __builtin_amdgcn_sched_barrier(0);
    cur = nxt;
  }

#pragma unroll
  for (int mi = 0; mi < 4; ++mi)
#pragma unroll
    for (int j = 0; j < 4; ++j) {
      int i = m0 + wm * 64 + mi * 16 + (l >> 4) * 4 + j;
#pragma unroll
      for (int ni = 0; ni < 4; ++ni) {
        int n = n0 + wn * 64 + ni * 16 + (l & 15);
        if (n <= FD) unsafeAtomicAdd(&U[((size_t)h * NN + i) * USTRIDE + n], acc[mi][ni][j]);
      }
    }
}

// ---------- y = elu(mean_h U[h][i][o] / U[h][i][FD]) ----------
__global__ __launch_bounds__(256) void k_final(const float* __restrict__ U,
                                               float* __restrict__ y) {
  int idx = blockIdx.x * 256 + threadIdx.x;
  if (idx >= NN * FD) return;
  int i = idx / FD, o = idx - i * FD;
  const size_t HS = (size_t)NN * USTRIDE;
  float s = 0.f;
#pragma unroll
  for (int h = 0; h < NH; ++h) {
    size_t b = h * HS + (size_t)i * USTRIDE;
    s += U[b + o] / U[b + FD];
  }
  s *= (1.f / 3.f);
  y[idx] = s > 0.f ? s : (expf(s) - 1.f);
}

extern "C" void kernel_launch(void* const* d_in, const int* in_sizes, int n_in,
                              void* d_out, int out_size, void* d_ws, size_t ws_size,
                              hipStream_t stream) {
  const float* x   = (const float*)d_in[0];
  const int*   adj = (const int*)d_in[1];
  const float* W   = (const float*)d_in[2];
  const float* a   = (const float*)d_in[3];
  float* y = (float*)d_out;

  char* ws = (char*)d_ws;
  size_t off = 0;
  auto alloc = [&](size_t bytes) {
    void* p = ws + off;
    off = (off + bytes + 255) & ~(size_t)255;
    return p;
  };
  unsigned short* xb  = (unsigned short*)alloc((size_t)NN * KPAD * 2);
  unsigned short* wt  = (unsigned short*)alloc((size_t)NH * OPAD * KPAD * 2);
  unsigned short* wht = (unsigned short*)alloc((size_t)NH * OPAD * NN * 2);
  float* e1s = (float*)alloc((size_t)NH * NN * 4);
  float* f1s = (float*)alloc((size_t)NH * NN * 4);
  float* e2s = (float*)alloc((size_t)NH * NN * 4);
  float* f2s = (float*)alloc((size_t)NH * NN * 4);
  uint64_t* bm = (uint64_t*)alloc((size_t)NN * 128 * 8);
  float* U = (float*)alloc((size_t)NH * NN * USTRIDE * 4);
  (void)ws_size; (void)in_sizes; (void)n_in; (void)out_size;

  k_cast_x<<<(NN * KPAD + 255) / 256, 256, 0, stream>>>(x, xb);
  k_cast_wt<<<(NH * OPAD * KPAD + 255) / 256, 256, 0, stream>>>(W, wt);
  k_pack<<<NN * 128 / 4, 256, 0, stream>>>(adj, bm);
  k_gemm_wht<<<dim3(OPAD / 128, NN / 256, NH), 512, 0, stream>>>(wt, xb, wht);
  k_a1a2<<<dim3(NN / 256, NH), 256, 0, stream>>>(wht, a, e1s, f1s, e2s, f2s);
  hipMemsetAsync(U, 0, (size_t)NH * NN * USTRIDE * 4, stream);
  k_pv<<<dim3(NN / 128, OPAD / 256, NH * KS), 512, 0, stream>>>(wht, e1s, f1s, e2s, f2s, bm, U);
  k_final<<<(NN * FD + 255) / 256, 256, 0, stream>>>(U, y);
}

// Round 6
// 714.946 us; speedup vs baseline: 1.6598x; 1.6598x over previous
//
#include <hip/hip_runtime.h>
#include <hip/hip_bf16.h>
#include <stdint.h>

#define NN 8192
#define FD 690
#define NH 3
#define KPAD 704   // F_IN padded to mult of 64
#define OPAD 768   // F_OUT padded to mult of 128 (row FD holds constant 1 -> Z column)
#define USTRIDE 704
#define KS 4       // K-split factor for k_pv
#define LOG2E 1.4426950408889634f

typedef __attribute__((ext_vector_type(8))) short bf16x8;
typedef __attribute__((ext_vector_type(4))) float f32x4;

typedef __attribute__((address_space(1))) const void gas_t;
typedef __attribute__((address_space(3))) void las_t;

__device__ __forceinline__ void async_ld16(const void* g, void* l) {
  __builtin_amdgcn_global_load_lds((gas_t*)g, (las_t*)l, 16, 0, 0);
}

__device__ __forceinline__ float bf2f(unsigned short u) {
  return __uint_as_float(((unsigned int)u) << 16);
}
__device__ __forceinline__ unsigned short f2bf(float f) {
  __hip_bfloat16 h = __float2bfloat16(f);
  return *reinterpret_cast<unsigned short*>(&h);
}
// r = bit[lane] of (hi:lo) ? e : 0 — mask forced scalar via readfirstlane upstream
__device__ __forceinline__ float selbit(float e, uint32_t lo, uint32_t hi) {
  uint64_t m = ((uint64_t)hi << 32) | lo;
  float r;
  asm("v_cndmask_b32 %0, 0, %1, %2" : "=v"(r) : "v"(e), "s"(m));
  return r;
}

// ---------- cast / pad ----------
__global__ __launch_bounds__(256) void k_cast_x(const float* __restrict__ x,
                                                unsigned short* __restrict__ xb) {
  int idx = blockIdx.x * 256 + threadIdx.x;
  if (idx >= NN * KPAD) return;
  int n = idx / KPAD, f = idx - n * KPAD;
  float v = (f < FD) ? x[(size_t)n * FD + f] : 0.f;
  xb[idx] = f2bf(v);
}

__global__ __launch_bounds__(256) void k_cast_wt(const float* __restrict__ W,
                                                 unsigned short* __restrict__ wt) {
  int idx = blockIdx.x * 256 + threadIdx.x;
  if (idx >= NH * OPAD * KPAD) return;
  int h = idx / (OPAD * KPAD);
  int rem = idx - h * OPAD * KPAD;
  int o = rem / KPAD, f = rem - o * KPAD;
  float v = (o < FD && f < FD) ? W[((size_t)h * FD + f) * FD + o] : 0.f;
  wt[idx] = f2bf(v);
}

// ---------- adjacency -> bitmask ----------
__global__ __launch_bounds__(256) void k_pack(const int* __restrict__ adj,
                                              uint64_t* __restrict__ bm) {
  int wid = (blockIdx.x * 256 + threadIdx.x) >> 6;
  int lane = threadIdx.x & 63;
  int i = wid >> 7, wj = wid & 127;
  int v = adj[(int64_t)i * NN + wj * 64 + lane];
  uint64_t m = __ballot(v > 0);
  if (lane == 0) bm[i * 128 + wj] = m;
}

// ---------- WhT[h][o][n] = sum_f x[n][f] W[h][f][o]  (bf16 out; row FD = 1.0) ----------
__global__ __launch_bounds__(512) void k_gemm_wht(const unsigned short* __restrict__ wt,
                                                  const unsigned short* __restrict__ xb,
                                                  unsigned short* __restrict__ wht) {
  const int m0 = blockIdx.x * 128;   // o
  const int n0 = blockIdx.y * 256;   // node
  const int h  = blockIdx.z;
  const int tid = threadIdx.x;
  const int w = tid >> 6, l = tid & 63;
  const int wm = w >> 2, wn = w & 3;
  __shared__ unsigned short As[128 * 64];
  __shared__ unsigned short Bs[256 * 64];
  const unsigned short* Ag = wt + (size_t)h * OPAD * KPAD;
  f32x4 acc[4][4] = {};
  for (int kt = 0; kt < KPAD / 64; ++kt) {
    const int k0 = kt * 64;
#pragma unroll
    for (int r = 0; r < 2; ++r) {
      const unsigned short* g = Ag + (size_t)(m0 + r * 64 + w * 8 + (l >> 3)) * KPAD + k0 + (l & 7) * 8;
      async_ld16(g, &As[(r * 64 + w * 8) * 64]);
    }
#pragma unroll
    for (int r = 0; r < 4; ++r) {
      const unsigned short* g = xb + (size_t)(n0 + r * 64 + w * 8 + (l >> 3)) * KPAD + k0 + (l & 7) * 8;
      async_ld16(g, &Bs[(r * 64 + w * 8) * 64]);
    }
    __syncthreads();
#pragma unroll
    for (int ks = 0; ks < 2; ++ks) {
      bf16x8 af[4], bfr[4];
#pragma unroll
      for (int mi = 0; mi < 4; ++mi)
        af[mi] = *reinterpret_cast<const bf16x8*>(
            &As[(wm * 64 + mi * 16 + (l & 15)) * 64 + ks * 32 + (l >> 4) * 8]);
#pragma unroll
      for (int ni = 0; ni < 4; ++ni)
        bfr[ni] = *reinterpret_cast<const bf16x8*>(
            &Bs[(wn * 64 + ni * 16 + (l & 15)) * 64 + ks * 32 + (l >> 4) * 8]);
#pragma unroll
      for (int mi = 0; mi < 4; ++mi)
#pragma unroll
        for (int ni = 0; ni < 4; ++ni)
          acc[mi][ni] = __builtin_amdgcn_mfma_f32_16x16x32_bf16(af[mi], bfr[ni], acc[mi][ni], 0, 0, 0);
    }
    __syncthreads();
  }
  unsigned short* Wh = wht + (size_t)h * OPAD * NN;
#pragma unroll
  for (int mi = 0; mi < 4; ++mi)
#pragma unroll
    for (int j = 0; j < 4; ++j) {
      int o = m0 + wm * 64 + mi * 16 + (l >> 4) * 4 + j;
#pragma unroll
      for (int ni = 0; ni < 4; ++ni) {
        int n = n0 + wn * 64 + ni * 16 + (l & 15);
        float val = (o == FD) ? 1.0f : acc[mi][ni][j];  // pad rows are exactly 0; row FD = ones
        Wh[(size_t)o * NN + n] = f2bf(val);
      }
    }
}

// ---------- per (head,node): E=2^(a*log2e), F=2^(0.2*a*log2e) for both halves ----------
__global__ __launch_bounds__(256) void k_a1a2(const unsigned short* __restrict__ wht,
                                              const float* __restrict__ a,
                                              float* __restrict__ e1s, float* __restrict__ f1s,
                                              float* __restrict__ e2s, float* __restrict__ f2s) {
  const int h = blockIdx.y;
  const int n = blockIdx.x * 256 + threadIdx.x;
  const unsigned short* Wp = wht + (size_t)h * OPAD * NN + n;
  const float* ap = a + h * 2 * FD;
  float s1 = 0.f, s2 = 0.f;
  for (int o = 0; o < FD; ++o) {
    float wv = bf2f(Wp[(size_t)o * NN]);
    s1 += wv * ap[o];
    s2 += wv * ap[FD + o];
  }
  e1s[h * NN + n] = exp2f(s1 * LOG2E);
  f1s[h * NN + n] = exp2f(0.2f * s1 * LOG2E);
  e2s[h * NN + n] = exp2f(s2 * LOG2E);
  f2s[h * NN + n] = exp2f(0.2f * s2 * LOG2E);
}

// ---------- PV: U[h][i][n] += sum_{j in kseg} w_ij WhT[n][j] ; column FD gives Z_i ----------
// w_ij = max(E1_i*E2_j, F1_i*F2_j)  (== exp2(log2e*lrelu(a1_i+a2_j)), exp2 monotone)
// Round-3 structure (measured: 0 bank conflicts, VGPR 64, 3 blocks/CU) with:
//  - e2/f2 prefetched one K-tile ahead into regs: genA has NO vmem dependency,
//    so the B gload_lds drain moves to the __syncthreads (covered by genA VALU)
//  - s_setprio around the MFMA cluster
__global__ __launch_bounds__(512) void k_pv(const unsigned short* __restrict__ wht,
                                            const float* __restrict__ e1s,
                                            const float* __restrict__ f1s,
                                            const float* __restrict__ e2s,
                                            const float* __restrict__ f2s,
                                            const uint64_t* __restrict__ bm,
                                            float* __restrict__ U) {
  const int m0 = blockIdx.x * 128;          // node rows i
  const int n0 = blockIdx.y * 256;          // feature cols
  const int h    = blockIdx.z / KS;
  const int kseg = blockIdx.z % KS;
  const int tid = threadIdx.x;
  const int w = tid >> 6, l = tid & 63;
  const int wu = __builtin_amdgcn_readfirstlane(w);
  const int wm = w >> 2, wn = w & 3;
  // XOR-swizzled [rows][64] tiles (16B-block index ^= row&7)
  __shared__ unsigned short As[128 * 64];
  __shared__ unsigned short Bs[256 * 64];
  const unsigned short* Bg = wht + (size_t)h * OPAD * NN;
  const uint64_t* bmw = bm + (size_t)(m0 + wu * 16) * 128;
  float E1v[16], F1v[16];
#pragma unroll
  for (int r = 0; r < 16; ++r) {
    E1v[r] = e1s[h * NN + m0 + wu * 16 + r];
    F1v[r] = f1s[h * NN + m0 + wu * 16 + r];
  }

  const int kt0 = kseg * (128 / KS);
  const int ktend = kt0 + 128 / KS;

  f32x4 acc[4][4] = {};

  // prologue: e2/f2 for the first K-tile
  float e2cur = e2s[h * NN + kt0 * 64 + l];
  float f2cur = f2s[h * NN + kt0 * 64 + l];

  for (int kt = kt0; kt < ktend; ++kt) {
    const int k0 = kt * 64;
    // stage B (Wh^T panel) async, source pre-swizzled so linear LDS dest = swizzled layout
#pragma unroll
    for (int r = 0; r < 4; ++r) {
      const unsigned short* g = Bg + (size_t)(n0 + r * 64 + wu * 8 + (l >> 3)) * NN
                                + k0 + ((l & 7) ^ (l >> 3)) * 8;
      async_ld16(g, &Bs[(r * 64 + wu * 8) * 64]);
    }
    // prefetch e2/f2 for the NEXT tile (used after the sync of this iter)
    float e2nxt = 0.f, f2nxt = 0.f;
    if (kt + 1 < ktend) {
      e2nxt = e2s[h * NN + (kt + 1) * 64 + l];
      f2nxt = f2s[h * NN + (kt + 1) * 64 + l];
    }
    // generate A tile: wave handles 16 rows, lane = k within tile (regs only + scalar masks)
#pragma unroll
    for (int r = 0; r < 16; ++r) {
      uint64_t mrow = bmw[(size_t)r * 128 + kt];
      uint32_t mlo = __builtin_amdgcn_readfirstlane((uint32_t)mrow);
      uint32_t mhi = __builtin_amdgcn_readfirstlane((uint32_t)(mrow >> 32));
      float e = fmaxf(E1v[r] * e2cur, F1v[r] * f2cur);
      e = selbit(e, mlo, mhi);
      As[(wu * 16 + r) * 64 + (l ^ ((r & 7) << 3))] = f2bf(e);
    }
    __syncthreads();

    __builtin_amdgcn_s_setprio(1);
#pragma unroll
    for (int ks = 0; ks < 2; ++ks) {
      bf16x8 af[4], bfr[4];
#pragma unroll
      for (int mi = 0; mi < 4; ++mi) {
        int row = wm * 64 + mi * 16 + (l & 15);
        af[mi] = *reinterpret_cast<const bf16x8*>(
            &As[row * 64 + (((ks * 4 + (l >> 4)) ^ (row & 7)) * 8)]);
      }
#pragma unroll
      for (int ni = 0; ni < 4; ++ni) {
        int row = wn * 64 + ni * 16 + (l & 15);
        bfr[ni] = *reinterpret_cast<const bf16x8*>(
            &Bs[row * 64 + (((ks * 4 + (l >> 4)) ^ (row & 7)) * 8)]);
      }
#pragma unroll
      for (int mi = 0; mi < 4; ++mi)
#pragma unroll
        for (int ni = 0; ni < 4; ++ni)
          acc[mi][ni] = __builtin_amdgcn_mfma_f32_16x16x32_bf16(af[mi], bfr[ni], acc[mi][ni], 0, 0, 0);
    }
    __builtin_amdgcn_s_setprio(0);
    __syncthreads();

    e2cur = e2nxt;
    f2cur = f2nxt;
  }

#pragma unroll
  for (int mi = 0; mi < 4; ++mi)
#pragma unroll
    for (int j = 0; j < 4; ++j) {
      int i = m0 + wm * 64 + mi * 16 + (l >> 4) * 4 + j;
#pragma unroll
      for (int ni = 0; ni < 4; ++ni) {
        int n = n0 + wn * 64 + ni * 16 + (l & 15);
        if (n <= FD) unsafeAtomicAdd(&U[((size_t)h * NN + i) * USTRIDE + n], acc[mi][ni][j]);
      }
    }
}

// ---------- y = elu(mean_h U[h][i][o] / U[h][i][FD]) ----------
__global__ __launch_bounds__(256) void k_final(const float* __restrict__ U,
                                               float* __restrict__ y) {
  int idx = blockIdx.x * 256 + threadIdx.x;
  if (idx >= NN * FD) return;
  int i = idx / FD, o = idx - i * FD;
  const size_t HS = (size_t)NN * USTRIDE;
  float s = 0.f;
#pragma unroll
  for (int h = 0; h < NH; ++h) {
    size_t b = h * HS + (size_t)i * USTRIDE;
    s += U[b + o] / U[b + FD];
  }
  s *= (1.f / 3.f);
  y[idx] = s > 0.f ? s : (expf(s) - 1.f);
}

extern "C" void kernel_launch(void* const* d_in, const int* in_sizes, int n_in,
                              void* d_out, int out_size, void* d_ws, size_t ws_size,
                              hipStream_t stream) {
  const float* x   = (const float*)d_in[0];
  const int*   adj = (const int*)d_in[1];
  const float* W   = (const float*)d_in[2];
  const float* a   = (const float*)d_in[3];
  float* y = (float*)d_out;

  char* ws = (char*)d_ws;
  size_t off = 0;
  auto alloc = [&](size_t bytes) {
    void* p = ws + off;
    off = (off + bytes + 255) & ~(size_t)255;
    return p;
  };
  unsigned short* xb  = (unsigned short*)alloc((size_t)NN * KPAD * 2);
  unsigned short* wt  = (unsigned short*)alloc((size_t)NH * OPAD * KPAD * 2);
  unsigned short* wht = (unsigned short*)alloc((size_t)NH * OPAD * NN * 2);
  float* e1s = (float*)alloc((size_t)NH * NN * 4);
  float* f1s = (float*)alloc((size_t)NH * NN * 4);
  float* e2s = (float*)alloc((size_t)NH * NN * 4);
  float* f2s = (float*)alloc((size_t)NH * NN * 4);
  uint64_t* bm = (uint64_t*)alloc((size_t)NN * 128 * 8);
  float* U = (float*)alloc((size_t)NH * NN * USTRIDE * 4);
  (void)ws_size; (void)in_sizes; (void)n_in; (void)out_size;

  k_cast_x<<<(NN * KPAD + 255) / 256, 256, 0, stream>>>(x, xb);
  k_cast_wt<<<(NH * OPAD * KPAD + 255) / 256, 256, 0, stream>>>(W, wt);
  k_pack<<<NN * 128 / 4, 256, 0, stream>>>(adj, bm);
  k_gemm_wht<<<dim3(OPAD / 128, NN / 256, NH), 512, 0, stream>>>(wt, xb, wht);
  k_a1a2<<<dim3(NN / 256, NH), 256, 0, stream>>>(wht, a, e1s, f1s, e2s, f2s);
  hipMemsetAsync(U, 0, (size_t)NH * NN * USTRIDE * 4, stream);
  k_pv<<<dim3(NN / 128, OPAD / 256, NH * KS), 512, 0, stream>>>(wht, e1s, f1s, e2s, f2s, bm, U);
  k_final<<<(NN * FD + 255) / 256, 256, 0, stream>>>(U, y);
}

// Round 7
// 637.279 us; speedup vs baseline: 1.8621x; 1.1219x over previous
//
#include <hip/hip_runtime.h>
#include <hip/hip_bf16.h>
#include <stdint.h>

#define NN 8192
#define FD 690
#define NH 3
#define KPAD 704   // F_IN padded to mult of 64
#define OPAD 768   // F_OUT padded to mult of 128 (row FD holds constant 1 -> Z column)
#define USTRIDE 704
#define KS 2       // K-split factor for k_pv
#define LOG2E 1.4426950408889634f

typedef __attribute__((ext_vector_type(8))) short bf16x8;
typedef __attribute__((ext_vector_type(4))) float f32x4;

typedef __attribute__((address_space(1))) const void gas_t;
typedef __attribute__((address_space(3))) void las_t;

__device__ __forceinline__ void async_ld16(const void* g, void* l) {
  __builtin_amdgcn_global_load_lds((gas_t*)g, (las_t*)l, 16, 0, 0);
}

__device__ __forceinline__ float bf2f(unsigned short u) {
  return __uint_as_float(((unsigned int)u) << 16);
}
__device__ __forceinline__ unsigned short f2bf(float f) {
  __hip_bfloat16 h = __float2bfloat16(f);
  return *reinterpret_cast<unsigned short*>(&h);
}
// r = bit[lane] of (hi:lo) ? e : 0 — mask forced scalar via readfirstlane upstream
__device__ __forceinline__ float selbit(float e, uint32_t lo, uint32_t hi) {
  uint64_t m = ((uint64_t)hi << 32) | lo;
  float r;
  asm("v_cndmask_b32 %0, 0, %1, %2" : "=v"(r) : "v"(e), "s"(m));
  return r;
}

// ---------- cast / pad ----------
__global__ __launch_bounds__(256) void k_cast_x(const float* __restrict__ x,
                                                unsigned short* __restrict__ xb) {
  int idx = blockIdx.x * 256 + threadIdx.x;
  if (idx >= NN * KPAD) return;
  int n = idx / KPAD, f = idx - n * KPAD;
  float v = (f < FD) ? x[(size_t)n * FD + f] : 0.f;
  xb[idx] = f2bf(v);
}

__global__ __launch_bounds__(256) void k_cast_wt(const float* __restrict__ W,
                                                 unsigned short* __restrict__ wt) {
  int idx = blockIdx.x * 256 + threadIdx.x;
  if (idx >= NH * OPAD * KPAD) return;
  int h = idx / (OPAD * KPAD);
  int rem = idx - h * OPAD * KPAD;
  int o = rem / KPAD, f = rem - o * KPAD;
  float v = (o < FD && f < FD) ? W[((size_t)h * FD + f) * FD + o] : 0.f;
  wt[idx] = f2bf(v);
}

// ---------- adjacency -> bitmask ----------
__global__ __launch_bounds__(256) void k_pack(const int* __restrict__ adj,
                                              uint64_t* __restrict__ bm) {
  int wid = (blockIdx.x * 256 + threadIdx.x) >> 6;
  int lane = threadIdx.x & 63;
  int i = wid >> 7, wj = wid & 127;
  int v = adj[(int64_t)i * NN + wj * 64 + lane];
  uint64_t m = __ballot(v > 0);
  if (lane == 0) bm[i * 128 + wj] = m;
}

// ---------- WhT[h][o][n] = sum_f x[n][f] W[h][f][o]  (bf16 out; row FD = 1.0) ----------
__global__ __launch_bounds__(512) void k_gemm_wht(const unsigned short* __restrict__ wt,
                                                  const unsigned short* __restrict__ xb,
                                                  unsigned short* __restrict__ wht) {
  const int m0 = blockIdx.x * 128;   // o
  const int n0 = blockIdx.y * 256;   // node
  const int h  = blockIdx.z;
  const int tid = threadIdx.x;
  const int w = tid >> 6, l = tid & 63;
  const int wm = w >> 2, wn = w & 3;
  __shared__ unsigned short As[128 * 64];
  __shared__ unsigned short Bs[256 * 64];
  const unsigned short* Ag = wt + (size_t)h * OPAD * KPAD;
  f32x4 acc[4][4] = {};
  for (int kt = 0; kt < KPAD / 64; ++kt) {
    const int k0 = kt * 64;
#pragma unroll
    for (int r = 0; r < 2; ++r) {
      const unsigned short* g = Ag + (size_t)(m0 + r * 64 + w * 8 + (l >> 3)) * KPAD + k0 + (l & 7) * 8;
      async_ld16(g, &As[(r * 64 + w * 8) * 64]);
    }
#pragma unroll
    for (int r = 0; r < 4; ++r) {
      const unsigned short* g = xb + (size_t)(n0 + r * 64 + w * 8 + (l >> 3)) * KPAD + k0 + (l & 7) * 8;
      async_ld16(g, &Bs[(r * 64 + w * 8) * 64]);
    }
    __syncthreads();
#pragma unroll
    for (int ks = 0; ks < 2; ++ks) {
      bf16x8 af[4], bfr[4];
#pragma unroll
      for (int mi = 0; mi < 4; ++mi)
        af[mi] = *reinterpret_cast<const bf16x8*>(
            &As[(wm * 64 + mi * 16 + (l & 15)) * 64 + ks * 32 + (l >> 4) * 8]);
#pragma unroll
      for (int ni = 0; ni < 4; ++ni)
        bfr[ni] = *reinterpret_cast<const bf16x8*>(
            &Bs[(wn * 64 + ni * 16 + (l & 15)) * 64 + ks * 32 + (l >> 4) * 8]);
#pragma unroll
      for (int mi = 0; mi < 4; ++mi)
#pragma unroll
        for (int ni = 0; ni < 4; ++ni)
          acc[mi][ni] = __builtin_amdgcn_mfma_f32_16x16x32_bf16(af[mi], bfr[ni], acc[mi][ni], 0, 0, 0);
    }
    __syncthreads();
  }
  unsigned short* Wh = wht + (size_t)h * OPAD * NN;
#pragma unroll
  for (int mi = 0; mi < 4; ++mi)
#pragma unroll
    for (int j = 0; j < 4; ++j) {
      int o = m0 + wm * 64 + mi * 16 + (l >> 4) * 4 + j;
#pragma unroll
      for (int ni = 0; ni < 4; ++ni) {
        int n = n0 + wn * 64 + ni * 16 + (l & 15);
        float val = (o == FD) ? 1.0f : acc[mi][ni][j];  // pad rows are exactly 0; row FD = ones
        Wh[(size_t)o * NN + n] = f2bf(val);
      }
    }
}

// ---------- per (head,node): E=2^(a*log2e), F=2^(0.2*a*log2e) for both halves ----------
__global__ __launch_bounds__(256) void k_a1a2(const unsigned short* __restrict__ wht,
                                              const float* __restrict__ a,
                                              float* __restrict__ e1s, float* __restrict__ f1s,
                                              float* __restrict__ e2s, float* __restrict__ f2s) {
  const int h = blockIdx.y;
  const int n = blockIdx.x * 256 + threadIdx.x;
  const unsigned short* Wp = wht + (size_t)h * OPAD * NN + n;
  const float* ap = a + h * 2 * FD;
  float s1 = 0.f, s2 = 0.f;
  for (int o = 0; o < FD; ++o) {
    float wv = bf2f(Wp[(size_t)o * NN]);
    s1 += wv * ap[o];
    s2 += wv * ap[FD + o];
  }
  e1s[h * NN + n] = exp2f(s1 * LOG2E);
  f1s[h * NN + n] = exp2f(0.2f * s1 * LOG2E);
  e2s[h * NN + n] = exp2f(s2 * LOG2E);
  f2s[h * NN + n] = exp2f(0.2f * s2 * LOG2E);
}

// ---------- PV: U[h][i][n] += sum_{j in kseg} w_ij WhT[n][j] ; column FD gives Z_i ----------
// w_ij = max(E1_i*E2_j, F1_i*F2_j)  (== exp2(log2e*lrelu(a1_i+a2_j)), exp2 monotone)
// BM=64 x BN=384 (2 feature panels instead of 3 -> A-gen cost -33%).
// Round-3 micro-structure: stage -> genA -> sync -> MFMA -> sync. No setprio.
// e2/f2 loaded BEFORE the gload_lds issues so genA waits only vmcnt(6).
// Resource budget: LDS 8+48=56KB (2 blocks/CU), acc 48 regs, VGPR target <=128.
__global__ __launch_bounds__(512, 4) void k_pv(const unsigned short* __restrict__ wht,
                                               const float* __restrict__ e1s,
                                               const float* __restrict__ f1s,
                                               const float* __restrict__ e2s,
                                               const float* __restrict__ f2s,
                                               const uint64_t* __restrict__ bm,
                                               float* __restrict__ U) {
  const int m0 = blockIdx.x * 64;           // node rows i
  const int n0 = blockIdx.y * 384;          // feature cols
  const int h    = blockIdx.z / KS;
  const int kseg = blockIdx.z % KS;
  const int tid = threadIdx.x;
  const int w = tid >> 6, l = tid & 63;
  const int wu = __builtin_amdgcn_readfirstlane(w);
  // XOR-swizzled [rows][64] tiles (16B-block index ^= row&7)
  __shared__ unsigned short As[64 * 64];    // 8KB
  __shared__ unsigned short Bs[384 * 64];   // 48KB
  const unsigned short* Bg = wht + (size_t)h * OPAD * NN;
  const uint64_t* bmw = bm + (size_t)(m0 + wu * 8) * 128;
  float E1v[8], F1v[8];
#pragma unroll
  for (int r = 0; r < 8; ++r) {
    E1v[r] = e1s[h * NN + m0 + wu * 8 + r];
    F1v[r] = f1s[h * NN + m0 + wu * 8 + r];
  }

  const int kt0 = kseg * (NN / 64 / KS);
  const int ktend = kt0 + NN / 64 / KS;

  f32x4 acc[4][3] = {};

  for (int kt = kt0; kt < ktend; ++kt) {
    const int k0 = kt * 64;
    // e2/f2 FIRST: genA's first use then waits vmcnt(6), not the staging drain
    const float e2v = e2s[h * NN + k0 + l];
    const float f2v = f2s[h * NN + k0 + l];
    // stage B (Wh^T panel) async: linear LDS dest, source k-block pre-swizzled
#pragma unroll
    for (int call = 0; call < 6; ++call) {
      int c = call * 512 + tid;             // 16B-chunk index in [0, 3072)
      int row = c >> 3;
      int kb  = c & 7;
      int kbs = kb ^ (row & 7);
      const unsigned short* g = Bg + (size_t)(n0 + row) * NN + k0 + kbs * 8;
      async_ld16(g, &Bs[(size_t)c * 8]);
    }
    // generate A tile: wave handles 8 rows, lane = k within tile
#pragma unroll
    for (int r = 0; r < 8; ++r) {
      uint64_t mrow = bmw[(size_t)r * 128 + kt];
      uint32_t mlo = __builtin_amdgcn_readfirstlane((uint32_t)mrow);
      uint32_t mhi = __builtin_amdgcn_readfirstlane((uint32_t)(mrow >> 32));
      float e = fmaxf(E1v[r] * e2v, F1v[r] * f2v);
      e = selbit(e, mlo, mhi);
      As[(wu * 8 + r) * 64 + (l ^ (r << 3))] = f2bf(e);
    }
    __syncthreads();

#pragma unroll
    for (int ks = 0; ks < 2; ++ks) {
      bf16x8 af[4], bfr[3];
#pragma unroll
      for (int mi = 0; mi < 4; ++mi) {
        int row = mi * 16 + (l & 15);
        af[mi] = *reinterpret_cast<const bf16x8*>(
            &As[row * 64 + (((ks * 4 + (l >> 4)) ^ (row & 7)) * 8)]);
      }
#pragma unroll
      for (int ni = 0; ni < 3; ++ni) {
        int row = w * 48 + ni * 16 + (l & 15);
        bfr[ni] = *reinterpret_cast<const bf16x8*>(
            &Bs[row * 64 + (((ks * 4 + (l >> 4)) ^ (row & 7)) * 8)]);
      }
#pragma unroll
      for (int mi = 0; mi < 4; ++mi)
#pragma unroll
        for (int ni = 0; ni < 3; ++ni)
          acc[mi][ni] = __builtin_amdgcn_mfma_f32_16x16x32_bf16(af[mi], bfr[ni], acc[mi][ni], 0, 0, 0);
    }
    __syncthreads();
  }

#pragma unroll
  for (int mi = 0; mi < 4; ++mi)
#pragma unroll
    for (int j = 0; j < 4; ++j) {
      int i = m0 + mi * 16 + (l >> 4) * 4 + j;
#pragma unroll
      for (int ni = 0; ni < 3; ++ni) {
        int n = n0 + w * 48 + ni * 16 + (l & 15);
        if (n <= FD) unsafeAtomicAdd(&U[((size_t)h * NN + i) * USTRIDE + n], acc[mi][ni][j]);
      }
    }
}

// ---------- y = elu(mean_h U[h][i][o] / U[h][i][FD]) ----------
__global__ __launch_bounds__(256) void k_final(const float* __restrict__ U,
                                               float* __restrict__ y) {
  int idx = blockIdx.x * 256 + threadIdx.x;
  if (idx >= NN * FD) return;
  int i = idx / FD, o = idx - i * FD;
  const size_t HS = (size_t)NN * USTRIDE;
  float s = 0.f;
#pragma unroll
  for (int h = 0; h < NH; ++h) {
    size_t b = h * HS + (size_t)i * USTRIDE;
    s += U[b + o] / U[b + FD];
  }
  s *= (1.f / 3.f);
  y[idx] = s > 0.f ? s : (expf(s) - 1.f);
}

extern "C" void kernel_launch(void* const* d_in, const int* in_sizes, int n_in,
                              void* d_out, int out_size, void* d_ws, size_t ws_size,
                              hipStream_t stream) {
  const float* x   = (const float*)d_in[0];
  const int*   adj = (const int*)d_in[1];
  const float* W   = (const float*)d_in[2];
  const float* a   = (const float*)d_in[3];
  float* y = (float*)d_out;

  char* ws = (char*)d_ws;
  size_t off = 0;
  auto alloc = [&](size_t bytes) {
    void* p = ws + off;
    off = (off + bytes + 255) & ~(size_t)255;
    return p;
  };
  unsigned short* xb  = (unsigned short*)alloc((size_t)NN * KPAD * 2);
  unsigned short* wt  = (unsigned short*)alloc((size_t)NH * OPAD * KPAD * 2);
  unsigned short* wht = (unsigned short*)alloc((size_t)NH * OPAD * NN * 2);
  float* e1s = (float*)alloc((size_t)NH * NN * 4);
  float* f1s = (float*)alloc((size_t)NH * NN * 4);
  float* e2s = (float*)alloc((size_t)NH * NN * 4);
  float* f2s = (float*)alloc((size_t)NH * NN * 4);
  uint64_t* bm = (uint64_t*)alloc((size_t)NN * 128 * 8);
  float* U = (float*)alloc((size_t)NH * NN * USTRIDE * 4);
  (void)ws_size; (void)in_sizes; (void)n_in; (void)out_size;

  k_cast_x<<<(NN * KPAD + 255) / 256, 256, 0, stream>>>(x, xb);
  k_cast_wt<<<(NH * OPAD * KPAD + 255) / 256, 256, 0, stream>>>(W, wt);
  k_pack<<<NN * 128 / 4, 256, 0, stream>>>(adj, bm);
  k_gemm_wht<<<dim3(OPAD / 128, NN / 256, NH), 512, 0, stream>>>(wt, xb, wht);
  k_a1a2<<<dim3(NN / 256, NH), 256, 0, stream>>>(wht, a, e1s, f1s, e2s, f2s);
  hipMemsetAsync(U, 0, (size_t)NH * NN * USTRIDE * 4, stream);
  k_pv<<<dim3(NN / 64, 2, NH * KS), 512, 0, stream>>>(wht, e1s, f1s, e2s, f2s, bm, U);
  k_final<<<(NN * FD + 255) / 256, 256, 0, stream>>>(U, y);
}